// Round 11
// baseline (434.382 us; speedup 1.0000x reference)
//
#include <hip/hip_runtime.h>
#include <math.h>

typedef long long I64;

// ---- problem constants ----
#define NB    8
#define NTOK  576
#define DIM   1024
#define NMASK 64
#define HMASK 384
#define WMASK 384
#define QDIM  4096
#define HDIM  1024
#define KREG  32
#define CCTX  128
#define GH    24
#define GW    24
#define GNUM  576

// ---- output layout (floats) ----
#define OFF_VIS 0
#define OFF_REG 1318912
#define OFF_CTX 1581056
#define OFF_BG  2629632
#define OFF_PP  2637824
#define OFF_RW  2642432
#define OFF_SEL 2647040
#define OFF_GV  2648064

// ---- workspace layout (floats) ----
#define WS_BS   0          // B*M*576
#define WS_NMAT 294912     // B*32*576
#define WS_SCK  442368     // B*32
#define WS_H1   442624     // B*32*1024
#define WS_Q    704768     // B*1024 (i<2048, +bq)
#define WS_Q2   712960     // B*1024 (i>=2048)
#define WS_GV   721152     // B
#define WS_PP   721160     // B*576
#define WS_CS   725768     // B*1024
#define WS_RS   733960     // B*576 final scores
#define WS_HID  775432     // B*576*1024 raw hid
#define WS_END  5494024    // floats (~22 MB)

#define QBLK      256
#define BS_BLOCKS (NB * NMASK * 24)   // 12288
#define HIDBLK    256                 // 8b x 4 tokTiles(144) x 8 colTiles
#define MEGA_GRID (HIDBLK + QBLK + BS_BLOCKS)

// ======================== MEGA: hid-GEMM-raw + q-GEMV + mask block sums ========================
// gid [0,256): hid GEMM 144x128 tile (9x8 thread tile), single-buffer 41.7KB -> WS_HID raw
// gid [256,512): q partial GEMV
// gid [512,12800): mask 16x16 block sums
// launch_bounds(256,3): 3 blocks/CU so bs blocks co-reside with the hid block and fill
// its barrier/LDS-latency stalls. setprio(1) biases arbitration to hid FMA waves.
__global__ __launch_bounds__(256, 3) void k_mega(
    const float* __restrict__ masks, const float* __restrict__ qe,
    const float* __restrict__ Wq, const float* __restrict__ bq,
    const float* __restrict__ pt, const float* __restrict__ Wv,
    float* __restrict__ ws) {
  int gid = blockIdx.x;
  int t = threadIdx.x;
  __shared__ __align__(16) float smem[10432];   // 41728 B

  if (gid < HIDBLK) {
    // ---- hid GEMM: BM=144, BN=128, BK=32, thread tile 9x8 ----
    int b = gid >> 5;
    int r = gid & 31;
    int tokTile = r >> 3;
    int colTile = r & 7;
    int n0 = tokTile * 144;
    int col0 = colTile * 128;
    int trow = t >> 4;
    int tcol = t & 15;

    float (*sA)[36]  = (float(*)[36])smem;            // 144x36
    float (*sW)[164] = (float(*)[164])(smem + 5184);  // 32x164

    float acc[9][8];
    #pragma unroll
    for (int i = 0; i < 9; ++i)
      #pragma unroll
      for (int j = 0; j < 8; ++j) acc[i][j] = 0.f;

    int a_row0 = t >> 3, a_kq = t & 7;
    int a_row1 = (t + 256) >> 3;
    int a_row2 = (t + 512) >> 3;
    int a_row3 = (t + 768) >> 3;
    int a_row4 = (t + 1024) >> 3;     // only t<128
    int w_k0 = t >> 5, w_c = t & 31;

    const float* ptb = pt + (I64)(b * NTOK + n0) * DIM;
    const float* wvb = Wv + col0;

    float4 pa0, pa1, pa2, pa3, pa4 = {0,0,0,0};
    float4 pw0, pw1, pw2, pw3;

    pa0 = *(const float4*)&ptb[(I64)a_row0 * DIM + a_kq * 4];
    pa1 = *(const float4*)&ptb[(I64)a_row1 * DIM + a_kq * 4];
    pa2 = *(const float4*)&ptb[(I64)a_row2 * DIM + a_kq * 4];
    pa3 = *(const float4*)&ptb[(I64)a_row3 * DIM + a_kq * 4];
    if (t < 128) pa4 = *(const float4*)&ptb[(I64)a_row4 * DIM + a_kq * 4];
    pw0 = *(const float4*)&wvb[(I64)(w_k0 +  0) * HDIM + w_c * 4];
    pw1 = *(const float4*)&wvb[(I64)(w_k0 +  8) * HDIM + w_c * 4];
    pw2 = *(const float4*)&wvb[(I64)(w_k0 + 16) * HDIM + w_c * 4];
    pw3 = *(const float4*)&wvb[(I64)(w_k0 + 24) * HDIM + w_c * 4];

    for (int s = 0; s < 32; ++s) {
      __syncthreads();
      *(float4*)&sA[a_row0][a_kq * 4] = pa0;
      *(float4*)&sA[a_row1][a_kq * 4] = pa1;
      *(float4*)&sA[a_row2][a_kq * 4] = pa2;
      *(float4*)&sA[a_row3][a_kq * 4] = pa3;
      if (t < 128) *(float4*)&sA[a_row4][a_kq * 4] = pa4;
      *(float4*)&sW[w_k0 +  0][w_c * 4] = pw0;
      *(float4*)&sW[w_k0 +  8][w_c * 4] = pw1;
      *(float4*)&sW[w_k0 + 16][w_c * 4] = pw2;
      *(float4*)&sW[w_k0 + 24][w_c * 4] = pw3;
      __syncthreads();
      if (s + 1 < 32) {
        int k0 = (s + 1) * 32;
        pa0 = *(const float4*)&ptb[(I64)a_row0 * DIM + k0 + a_kq * 4];
        pa1 = *(const float4*)&ptb[(I64)a_row1 * DIM + k0 + a_kq * 4];
        pa2 = *(const float4*)&ptb[(I64)a_row2 * DIM + k0 + a_kq * 4];
        pa3 = *(const float4*)&ptb[(I64)a_row3 * DIM + k0 + a_kq * 4];
        if (t < 128) pa4 = *(const float4*)&ptb[(I64)a_row4 * DIM + k0 + a_kq * 4];
        pw0 = *(const float4*)&wvb[(I64)(k0 + w_k0 +  0) * HDIM + w_c * 4];
        pw1 = *(const float4*)&wvb[(I64)(k0 + w_k0 +  8) * HDIM + w_c * 4];
        pw2 = *(const float4*)&wvb[(I64)(k0 + w_k0 + 16) * HDIM + w_c * 4];
        pw3 = *(const float4*)&wvb[(I64)(k0 + w_k0 + 24) * HDIM + w_c * 4];
      }
      __builtin_amdgcn_s_setprio(1);
      #pragma unroll 2
      for (int kk4 = 0; kk4 < 8; ++kk4) {
        float4 af[9];
        #pragma unroll
        for (int i = 0; i < 9; ++i)
          af[i] = *(const float4*)&sA[trow * 9 + i][kk4 * 4];
        float4 w0[4], w1[4];
        #pragma unroll
        for (int m = 0; m < 4; ++m) {
          w0[m] = *(const float4*)&sW[kk4 * 4 + m][tcol * 4];
          w1[m] = *(const float4*)&sW[kk4 * 4 + m][64 + tcol * 4];
        }
        #pragma unroll
        for (int i = 0; i < 9; ++i) {
          #pragma unroll
          for (int m = 0; m < 4; ++m) {
            float a = ((const float*)&af[i])[m];
            acc[i][0] = fmaf(a, w0[m].x, acc[i][0]);
            acc[i][1] = fmaf(a, w0[m].y, acc[i][1]);
            acc[i][2] = fmaf(a, w0[m].z, acc[i][2]);
            acc[i][3] = fmaf(a, w0[m].w, acc[i][3]);
            acc[i][4] = fmaf(a, w1[m].x, acc[i][4]);
            acc[i][5] = fmaf(a, w1[m].y, acc[i][5]);
            acc[i][6] = fmaf(a, w1[m].z, acc[i][6]);
            acc[i][7] = fmaf(a, w1[m].w, acc[i][7]);
          }
        }
      }
      __builtin_amdgcn_s_setprio(0);
    }
    float* hid = ws + WS_HID + ((I64)b * NTOK + n0) * HDIM;
    #pragma unroll
    for (int i = 0; i < 9; ++i) {
      int row = trow * 9 + i;
      float4 va = {acc[i][0], acc[i][1], acc[i][2], acc[i][3]};
      float4 vb = {acc[i][4], acc[i][5], acc[i][6], acc[i][7]};
      *(float4*)&hid[(I64)row * HDIM + col0 + tcol * 4] = va;
      *(float4*)&hid[(I64)row * HDIM + col0 + 64 + tcol * 4] = vb;
    }
  } else if (gid < HIDBLK + QBLK) {
    // ---- q partial GEMV ----
    int g = gid - HIDBLK;
    int b = g >> 5, r = g & 31;
    int qb = r >> 1, ih = r & 1;
    int base = ih * 2048;
    float* qs = smem;
    float (*sp)[64] = (float(*)[64])(smem + 2048);
    const float4* s4 = (const float4*)(qe + (I64)b * QDIM + base);
    *(float4*)&qs[t * 4] = s4[t];
    *(float4*)&qs[(t + 256) * 4] = s4[t + 256];
    __syncthreads();
    int dl = t & 63, ig = t >> 6;
    int d = qb * 64 + dl;
    const float* wq = Wq + d;
    float a0 = 0.f, a1 = 0.f, a2 = 0.f, a3 = 0.f;
    float a4 = 0.f, a5 = 0.f, a6 = 0.f, a7 = 0.f;
    for (int i = ig; i < 2048; i += 32) {
      a0 = fmaf(qs[i],      wq[(I64)(base + i) * HDIM],      a0);
      a1 = fmaf(qs[i + 4],  wq[(I64)(base + i + 4) * HDIM],  a1);
      a2 = fmaf(qs[i + 8],  wq[(I64)(base + i + 8) * HDIM],  a2);
      a3 = fmaf(qs[i + 12], wq[(I64)(base + i + 12) * HDIM], a3);
      a4 = fmaf(qs[i + 16], wq[(I64)(base + i + 16) * HDIM], a4);
      a5 = fmaf(qs[i + 20], wq[(I64)(base + i + 20) * HDIM], a5);
      a6 = fmaf(qs[i + 24], wq[(I64)(base + i + 24) * HDIM], a6);
      a7 = fmaf(qs[i + 28], wq[(I64)(base + i + 28) * HDIM], a7);
    }
    sp[ig][dl] = ((a0 + a1) + (a2 + a3)) + ((a4 + a5) + (a6 + a7));
    __syncthreads();
    if (t < 64) {
      float s2 = (sp[0][t] + sp[1][t]) + (sp[2][t] + sp[3][t]);
      int dd = qb * 64 + t;
      ws[(ih ? WS_Q2 : WS_Q) + (I64)b * HDIM + dd] = s2 + (ih ? 0.f : bq[dd]);
    }
  } else {
    // ---- mask 16x16 block sums ----
    int g = gid - (HIDBLK + QBLK);
    int yband = g % 24;
    int bm = g / 24;
    float (*sm)[96] = (float(*)[96])smem;
    const float4* src = (const float4*)(masks + (I64)bm * (HMASK * WMASK) + (I64)yband * 16 * WMASK);
    #pragma unroll
    for (int j = 0; j < 6; ++j) {
      int f = t + 256 * j;
      float4 v = src[f];
      sm[f / 96][f % 96] = (v.x + v.y) + (v.z + v.w);
    }
    __syncthreads();
    if (t < 24) {
      float tt = 0.f;
      #pragma unroll
      for (int rr = 0; rr < 16; ++rr)
        #pragma unroll
        for (int c = 0; c < 4; ++c) tt += sm[rr][t * 4 + c];
      ws[WS_BS + (I64)bm * GNUM + yband * 24 + t] = tt;
    }
  }
}

// ======================== K2: per-batch small ops (LDS-staged) ========================
#define MGPAD 580
__global__ __launch_bounds__(256) void k_perbatch(
    const float* __restrict__ bs, const float* __restrict__ scores,
    const float* __restrict__ W1, const float* __restrict__ b1,
    float* __restrict__ ws, float* __restrict__ out) {
  int b = blockIdx.x;
  int t = threadIdx.x;
  __shared__ float s_mg[KREG][MGPAD];
  __shared__ float s_sc[NMASK];
  __shared__ float s_msum[NMASK];
  __shared__ int   s_order[NMASK];
  __shared__ float s_sck[KREG];
  __shared__ int   s_valid[KREG];
  __shared__ int   s_midx[KREG];
  __shared__ float s_rowsum[KREG];
  __shared__ float s_pp[GNUM];
  __shared__ float s_geom[KREG][5];
  __shared__ float s_red[64];
  __shared__ int   s_gv;
  __shared__ float s_ppsum;

  {
    int m = t >> 2, q = t & 3;
    const float4* p = (const float4*)(bs + ((I64)b * NMASK + m) * GNUM) + q * 36;
    float s = 0.f;
    #pragma unroll 4
    for (int j = 0; j < 36; ++j) {
      float4 v = p[j];
      s += v.x; s += v.y; s += v.z; s += v.w;
    }
    s += __shfl_xor(s, 1);
    s += __shfl_xor(s, 2);
    if (q == 0) s_msum[m] = s;
  }
  if (t < NMASK) s_sc[t] = scores[b * NMASK + t];
  __syncthreads();
  if (t == 0) {
    int g = 0;
    for (int m = 0; m < NMASK; ++m) g |= (s_msum[m] > 0.f) ? 1 : 0;
    s_gv = g;
  }
  if (t < NMASK) {
    float v = s_sc[t];
    int r = 0;
    for (int j = 0; j < NMASK; ++j) {
      float vj = s_sc[j];
      r += (vj > v) || (vj == v && j < t);
    }
    s_order[r] = t;
  }
  __syncthreads();
  const int gv = s_gv;
  if (t < KREG) {
    int m = s_order[t];
    float sc = s_sc[m];
    int valid = (sc >= 0.5f) ? 1 : 0;
    s_midx[t] = m;
    s_valid[t] = valid;
    float sck = gv ? (valid ? sc : 0.f) : 1.f;
    s_sck[t] = sck;
    ws[WS_SCK + b * KREG + t] = sck;
  }
  __syncthreads();
  {
    int k = t >> 3, sub = t & 7;
    const float inv256 = 1.f / 256.f;
    const float invN = 1.f / 576.f;
    float scale = gv ? (s_valid[k] ? inv256 : 0.f) : 0.f;
    float addv  = gv ? 0.f : invN;
    const float4* src = (const float4*)(bs + ((I64)b * NMASK + s_midx[k]) * GNUM) + sub * 18;
    float* dst = &s_mg[k][sub * 72];
    #pragma unroll 3
    for (int j = 0; j < 18; ++j) {
      float4 v = src[j];
      v.x = v.x * scale + addv;
      v.y = v.y * scale + addv;
      v.z = v.z * scale + addv;
      v.w = v.w * scale + addv;
      *(float4*)(dst + j * 4) = v;
    }
  }
  __syncthreads();
  {
    int k = t >> 3, sub = t & 7;
    float part = 0.f;
    for (int n = sub; n < GNUM; n += 8) part += fmaxf(s_mg[k][n], 0.f);
    part += __shfl_xor(part, 1);
    part += __shfl_xor(part, 2);
    part += __shfl_xor(part, 4);
    if (sub == 0) s_rowsum[k] = part;
  }
  __syncthreads();
  for (int idx = t; idx < KREG * GNUM; idx += 256) {
    int k = idx / GNUM, n = idx - k * GNUM;
    float v = fmaxf(s_mg[k][n], 0.f);
    ws[WS_NMAT + ((I64)b * KREG + k) * GNUM + n] = v / fmaxf(s_rowsum[k], 1e-6f);
  }
  for (int n = t; n < GNUM; n += 256) {
    float raw = 0.f;
    #pragma unroll
    for (int k = 0; k < KREG; ++k) raw = fmaf(s_mg[k][n], s_sck[k], raw);
    s_pp[n] = fmaxf(raw, 0.f);
  }
  __syncthreads();
  if (t < 64) {
    float s = 0.f;
    for (int n = t; n < GNUM; n += 64) s += s_pp[n];
    s_red[t] = s;
  }
  __syncthreads();
  if (t == 0) {
    float s = 0.f;
    for (int i = 0; i < 64; ++i) s += s_red[i];
    s_ppsum = s;
  }
  __syncthreads();
  {
    const float invN = 1.f / 576.f;
    float den = fmaxf(s_ppsum, 1e-6f);
    for (int n = t; n < GNUM; n += 256) {
      float v = gv ? (s_pp[n] / den) : invN;
      ws[WS_PP + b * GNUM + n] = v;
      out[OFF_PP + b * GNUM + n] = v;
    }
  }
  {
    int k = t >> 3, sub = t & 7;
    unsigned colmask = 0u;
    int ymin = GH, ymax = -1, cnt = 0;
    #pragma unroll
    for (int yy = 0; yy < 3; ++yy) {
      int y = sub * 3 + yy;
      unsigned rowm = 0u;
      for (int x = 0; x < GW; ++x)
        if (s_mg[k][y * GW + x] > 0.05f) rowm |= (1u << x);
      if (rowm) { if (y < ymin) ymin = y; if (y > ymax) ymax = y; }
      colmask |= rowm;
      cnt += __popc(rowm);
    }
    #pragma unroll
    for (int off = 1; off < 8; off <<= 1) {
      colmask |= (unsigned)__shfl_xor((int)colmask, off);
      cnt += __shfl_xor(cnt, off);
      int o1 = __shfl_xor(ymin, off); ymin = (o1 < ymin) ? o1 : ymin;
      int o2 = __shfl_xor(ymax, off); ymax = (o2 > ymax) ? o2 : ymax;
    }
    if (sub == 0) {
      float g0, g1, g2, g3, g4;
      if (cnt > 0) {
        int xmin = __ffs(colmask) - 1;
        int xmax = 31 - __clz(colmask);
        g0 = (float)xmin / 23.f;
        g1 = (float)ymin / 23.f;
        g2 = (float)xmax / 23.f;
        g3 = (float)ymax / 23.f;
        g4 = (float)cnt / 576.f;
      } else { g0 = g1 = g2 = g3 = g4 = 0.f; }
      s_geom[k][0] = g0; s_geom[k][1] = g1; s_geom[k][2] = g2;
      s_geom[k][3] = g3; s_geom[k][4] = g4;
    }
  }
  __syncthreads();
  for (int idx = t; idx < KREG * HDIM; idx += 256) {
    int k = idx >> 10, j = idx & 1023;
    float x = 0.f;
    #pragma unroll
    for (int i = 0; i < 5; ++i) x += s_geom[k][i] * W1[i * HDIM + j];
    x += b1[j];
    float sg = 1.f / (1.f + expf(-x));
    ws[WS_H1 + ((I64)b * KREG + k) * HDIM + j] = x * sg;
  }
  if (t == 0) {
    float g = gv ? 1.f : 0.f;
    ws[WS_GV + b] = g;
    out[OFF_GV + b] = g;
  }
}

// ======================== K3: region + colsum + epilogue (merged, NO fused softmax) ========================
__global__ __launch_bounds__(512) void k_regepi(
    const float* __restrict__ pt, const float* __restrict__ W2,
    const float* __restrict__ b2, const float* __restrict__ te,
    const float* __restrict__ bv, const float* __restrict__ bp,
    const float* __restrict__ Wp, const float* __restrict__ Wo,
    const float* __restrict__ bo,
    float* __restrict__ ws, float* __restrict__ out) {
  int blk = blockIdx.x;
  int t = threadIdx.x;
  if (blk < 512) {
    int b = blk >> 6, kg = (blk >> 3) & 7, dg = blk & 7;
    int dl = t & 127;
    int qh = t >> 7;
    int d = dg * 128 + dl;
    const float* nmb = ws + WS_NMAT + ((I64)b * KREG + kg * 4) * GNUM;
    const float* h1b = ws + WS_H1 + ((I64)b * KREG + kg * 4) * HDIM;
    float accP[4] = {0, 0, 0, 0};
    float accG[4] = {0, 0, 0, 0};
    float accS = 0.f;
    int n0 = qh * 144, n1 = n0 + 144;
    for (int n = n0; n < n1; ++n) {
      float p = pt[((I64)b * NTOK + n) * DIM + d];
      accS += p;
      #pragma unroll
      for (int kk = 0; kk < 4; ++kk)
        accP[kk] = fmaf(nmb[kk * GNUM + n], p, accP[kk]);
    }
    int j0 = qh * 256, j1 = j0 + 256;
    for (int j = j0; j < j1; ++j) {
      float wv = W2[(I64)j * DIM + d];
      #pragma unroll
      for (int kk = 0; kk < 4; ++kk)
        accG[kk] = fmaf(h1b[kk * HDIM + j], wv, accG[kk]);
    }
    __shared__ float cmbP[4][4][128];
    __shared__ float cmbG[4][4][128];
    __shared__ float cmbS[4][128];
    #pragma unroll
    for (int kk = 0; kk < 4; ++kk) {
      cmbP[qh][kk][dl] = accP[kk];
      cmbG[qh][kk][dl] = accG[kk];
    }
    cmbS[qh][dl] = accS;
    __syncthreads();
    if (qh == 0) {
      float bb = b2[d], t0 = te[d];
      #pragma unroll
      for (int kk = 0; kk < 4; ++kk) {
        int k = kg * 4 + kk;
        float P = (cmbP[0][kk][dl] + cmbP[1][kk][dl]) + (cmbP[2][kk][dl] + cmbP[3][kk][dl]);
        float G = (cmbG[0][kk][dl] + cmbG[1][kk][dl]) + (cmbG[2][kk][dl] + cmbG[3][kk][dl]);
        float val = P * ws[WS_SCK + b * KREG + k] + G + bb + t0;
        out[OFF_REG + ((I64)b * KREG + k) * DIM + d] = val;
        out[OFF_VIS + ((I64)b * 161 + k) * DIM + d] = val;
      }
      if (kg == 0)
        ws[WS_CS + (I64)b * DIM + d] =
            (cmbS[0][dl] + cmbS[1][dl]) + (cmbS[2][dl] + cmbS[3][dl]);
    }
  } else {
    int g = (blk - 512) * 32 + (t >> 4);
    int l = t & 15;
    int b = g / NTOK, n = g % NTOK;
    const float* hid = ws + WS_HID + (I64)g * HDIM;
    const float* q1 = ws + WS_Q + (I64)b * HDIM;
    const float* q2 = ws + WS_Q2 + (I64)b * HDIM;
    float ppv = ws[WS_PP + b * GNUM + n];
    float ssum = 0.f;
    #pragma unroll 4
    for (int j = 0; j < 16; ++j) {
      int c = l * 64 + j * 4;
      float4 h4 = *(const float4*)&hid[c];
      float4 b4 = *(const float4*)&bv[c];
      float4 p4 = *(const float4*)&bp[c];
      float4 w4 = *(const float4*)&Wp[c];
      float4 o4 = *(const float4*)&Wo[c];
      float4 qa = *(const float4*)&q1[c];
      float4 qb = *(const float4*)&q2[c];
      ssum = fmaf(o4.x, tanhf(h4.x + b4.x + p4.x + qa.x + qb.x + ppv * w4.x), ssum);
      ssum = fmaf(o4.y, tanhf(h4.y + b4.y + p4.y + qa.y + qb.y + ppv * w4.y), ssum);
      ssum = fmaf(o4.z, tanhf(h4.z + b4.z + p4.z + qa.z + qb.z + ppv * w4.z), ssum);
      ssum = fmaf(o4.w, tanhf(h4.w + b4.w + p4.w + qa.w + qb.w + ppv * w4.w), ssum);
    }
    ssum += __shfl_xor(ssum, 1);
    ssum += __shfl_xor(ssum, 2);
    ssum += __shfl_xor(ssum, 4);
    ssum += __shfl_xor(ssum, 8);
    if (l == 0) ws[WS_RS + g] = ssum + bo[0];
  }
}

// ======================== K4: softmax + stable top-k ========================
__global__ __launch_bounds__(576) void k_soft2(float* __restrict__ ws, float* __restrict__ out) {
  int b = blockIdx.x, t = threadIdx.x;
  __shared__ float s_rs[NTOK];
  __shared__ float s_w[9];
  __shared__ float s_max, s_sum;
  s_rs[t] = ws[WS_RS + b * NTOK + t];
  __syncthreads();
  float v = s_rs[t];
  int r = 0;
  for (int j = 0; j < NTOK; ++j) {
    float vj = s_rs[j];
    r += (vj > v) || (vj == v && j < t);
  }
  float m = v;
  for (int off = 1; off < 64; off <<= 1) m = fmaxf(m, __shfl_xor(m, off));
  if ((t & 63) == 0) s_w[t >> 6] = m;
  __syncthreads();
  if (t == 0) {
    float mm = s_w[0];
    for (int i = 1; i < 9; ++i) mm = fmaxf(mm, s_w[i]);
    s_max = mm;
  }
  __syncthreads();
  float e = expf(v - s_max);
  float s = e;
  for (int off = 1; off < 64; off <<= 1) s += __shfl_xor(s, off);
  if ((t & 63) == 0) s_w[t >> 6] = s;
  __syncthreads();
  if (t == 0) {
    float ss = 0.f;
    for (int i = 0; i < 9; ++i) ss += s_w[i];
    s_sum = ss;
  }
  __syncthreads();
  out[OFF_RW + b * NTOK + t] = e / s_sum;
  if (r < CCTX) out[OFF_SEL + b * CCTX + r] = (float)t;
}

// ======================== K5: context gather + background (parallel bg) ========================
__global__ __launch_bounds__(256) void k_post(const float* __restrict__ pt, const float* __restrict__ te,
                                              const float* __restrict__ ws, const float* __restrict__ outr,
                                              float* __restrict__ out) {
  int rr = blockIdx.x, b = blockIdx.y;
  if (rr < CCTX) {
    int d = threadIdx.x * 4;
    int idx = (int)outr[OFF_SEL + b * CCTX + rr];
    float4 v = *(const float4*)&pt[((I64)b * NTOK + idx) * DIM + d];
    float4 e = *(const float4*)&te[DIM + d];
    v.x += e.x; v.y += e.y; v.z += e.z; v.w += e.w;
    *(float4*)&out[OFF_CTX + ((I64)b * CCTX + rr) * DIM + d] = v;
    *(float4*)&out[OFF_VIS + ((I64)b * 161 + KREG + rr) * DIM + d] = v;
  } else {
    int dl = threadIdx.x & 63;
    int rg = threadIdx.x >> 6;
    __shared__ float4 cmb[4][64];
    #pragma unroll
    for (int dd = 0; dd < 4; ++dd) {
      int d = (dd * 64 + dl) * 4;
      float4 s = {0.f, 0.f, 0.f, 0.f};
      for (int r = rg * 32; r < rg * 32 + 32; ++r) {
        int idx = (int)outr[OFF_SEL + b * CCTX + r];
        float4 v = *(const float4*)&pt[((I64)b * NTOK + idx) * DIM + d];
        s.x += v.x; s.y += v.y; s.z += v.z; s.w += v.w;
      }
      cmb[rg][dl] = s;
      __syncthreads();
      if (rg == 0) {
        float4 s0 = cmb[0][dl], s1 = cmb[1][dl], s2 = cmb[2][dl], s3 = cmb[3][dl];
        float4 cs = *(const float4*)&ws[WS_CS + (I64)b * DIM + d];
        const float rinv = 1.f / 448.f;
        float4 e = *(const float4*)&te[2 * DIM + d];
        float4 o;
        o.x = (cs.x - ((s0.x + s1.x) + (s2.x + s3.x))) * rinv + e.x;
        o.y = (cs.y - ((s0.y + s1.y) + (s2.y + s3.y))) * rinv + e.y;
        o.z = (cs.z - ((s0.z + s1.z) + (s2.z + s3.z))) * rinv + e.z;
        o.w = (cs.w - ((s0.w + s1.w) + (s2.w + s3.w))) * rinv + e.w;
        *(float4*)&out[OFF_BG + (I64)b * DIM + d] = o;
        *(float4*)&out[OFF_VIS + ((I64)b * 161 + 160) * DIM + d] = o;
      }
      __syncthreads();
    }
  }
}

// ======================== launcher ========================
extern "C" void kernel_launch(void* const* d_in, const int* in_sizes, int n_in,
                              void* d_out, int out_size, void* d_ws, size_t ws_size,
                              hipStream_t stream) {
  (void)in_sizes; (void)n_in; (void)out_size; (void)ws_size;
  const float* pt     = (const float*)d_in[0];
  const float* masks  = (const float*)d_in[1];
  const float* scores = (const float*)d_in[2];
  const float* qe     = (const float*)d_in[3];
  const float* W1     = (const float*)d_in[4];
  const float* b1     = (const float*)d_in[5];
  const float* W2     = (const float*)d_in[6];
  const float* b2     = (const float*)d_in[7];
  const float* Wv     = (const float*)d_in[8];
  const float* bv     = (const float*)d_in[9];
  const float* Wp     = (const float*)d_in[10];
  const float* bp     = (const float*)d_in[11];
  const float* Wq     = (const float*)d_in[12];
  const float* bq     = (const float*)d_in[13];
  const float* Wo     = (const float*)d_in[14];
  const float* bo     = (const float*)d_in[15];
  const float* te     = (const float*)d_in[16];
  float* out = (float*)d_out;
  float* ws  = (float*)d_ws;

  k_mega<<<dim3(MEGA_GRID), dim3(256), 0, stream>>>(masks, qe, Wq, bq, pt, Wv, ws);
  k_perbatch<<<dim3(NB), dim3(256), 0, stream>>>(ws + WS_BS, scores, W1, b1, ws, out);
  k_regepi<<<dim3(512 + 144), dim3(512), 0, stream>>>(pt, W2, b2, te, bv, bp, Wp, Wo, bo, ws, out);
  k_soft2<<<dim3(NB), dim3(576), 0, stream>>>(ws, out);
  k_post<<<dim3(CCTX + 1, NB), dim3(256), 0, stream>>>(pt, te, ws, out, out);
}

// Round 12
// 326.256 us; speedup vs baseline: 1.3314x; 1.3314x over previous
//
#include <hip/hip_runtime.h>
#include <math.h>

typedef long long I64;

// ---- problem constants ----
#define NB    8
#define NTOK  576
#define DIM   1024
#define NMASK 64
#define HMASK 384
#define WMASK 384
#define QDIM  4096
#define HDIM  1024
#define KREG  32
#define CCTX  128
#define GH    24
#define GW    24
#define GNUM  576

// ---- output layout (floats) ----
#define OFF_VIS 0
#define OFF_REG 1318912
#define OFF_CTX 1581056
#define OFF_BG  2629632
#define OFF_PP  2637824
#define OFF_RW  2642432
#define OFF_SEL 2647040
#define OFF_GV  2648064

// ---- workspace layout (floats) ----
#define WS_BS   0          // B*M*576
#define WS_NMAT 294912     // B*32*576
#define WS_SCK  442368     // B*32
#define WS_H1   442624     // B*32*1024
#define WS_Q    704768     // B*1024 (i<2048, +bq)
#define WS_Q2   712960     // B*1024 (i>=2048)
#define WS_GV   721152     // B
#define WS_PP   721160     // B*576
#define WS_CS   725768     // B*1024
#define WS_RS   733960     // B*576 final scores
#define WS_HID  775432     // B*576*1024 raw hid
#define WS_END  5494024    // floats (~22 MB)

#define QBLK      256
#define BS_BLOCKS (NB * NMASK * 24)   // 12288
#define HIDBLK    256                 // 8b x 4 tokTiles(144) x 8 colTiles
#define MEGA_GRID (HIDBLK + QBLK + BS_BLOCKS)

// ======================== MEGA: hid-GEMM-raw + q-GEMV + mask block sums ========================
// gid [0,256): hid GEMM 144x128 tile (9x8 thread tile), single-buffer 41.7KB -> WS_HID raw
// gid [256,512): q partial GEMV
// gid [512,12800): mask 16x16 block sums
// launch_bounds(256,2): VGPR ~120, NO spill (bounds(256,3) capped regs at 84 and spilled
// ~50MB scratch traffic per dispatch — R11 regression). bs blocks co-reside (2 blocks/CU)
// and fill hid's barrier/LDS-latency stalls.
__global__ __launch_bounds__(256, 2) void k_mega(
    const float* __restrict__ masks, const float* __restrict__ qe,
    const float* __restrict__ Wq, const float* __restrict__ bq,
    const float* __restrict__ pt, const float* __restrict__ Wv,
    float* __restrict__ ws) {
  int gid = blockIdx.x;
  int t = threadIdx.x;
  __shared__ __align__(16) float smem[10432];   // 41728 B

  if (gid < HIDBLK) {
    // ---- hid GEMM: BM=144, BN=128, BK=32, thread tile 9x8 ----
    int b = gid >> 5;
    int r = gid & 31;
    int tokTile = r >> 3;
    int colTile = r & 7;
    int n0 = tokTile * 144;
    int col0 = colTile * 128;
    int trow = t >> 4;
    int tcol = t & 15;

    float (*sA)[36]  = (float(*)[36])smem;            // 144x36
    float (*sW)[164] = (float(*)[164])(smem + 5184);  // 32x164

    float acc[9][8];
    #pragma unroll
    for (int i = 0; i < 9; ++i)
      #pragma unroll
      for (int j = 0; j < 8; ++j) acc[i][j] = 0.f;

    int a_row0 = t >> 3, a_kq = t & 7;
    int a_row1 = (t + 256) >> 3;
    int a_row2 = (t + 512) >> 3;
    int a_row3 = (t + 768) >> 3;
    int a_row4 = (t + 1024) >> 3;     // only t<128
    int w_k0 = t >> 5, w_c = t & 31;

    const float* ptb = pt + (I64)(b * NTOK + n0) * DIM;
    const float* wvb = Wv + col0;

    float4 pa0, pa1, pa2, pa3, pa4 = {0,0,0,0};
    float4 pw0, pw1, pw2, pw3;

    pa0 = *(const float4*)&ptb[(I64)a_row0 * DIM + a_kq * 4];
    pa1 = *(const float4*)&ptb[(I64)a_row1 * DIM + a_kq * 4];
    pa2 = *(const float4*)&ptb[(I64)a_row2 * DIM + a_kq * 4];
    pa3 = *(const float4*)&ptb[(I64)a_row3 * DIM + a_kq * 4];
    if (t < 128) pa4 = *(const float4*)&ptb[(I64)a_row4 * DIM + a_kq * 4];
    pw0 = *(const float4*)&wvb[(I64)(w_k0 +  0) * HDIM + w_c * 4];
    pw1 = *(const float4*)&wvb[(I64)(w_k0 +  8) * HDIM + w_c * 4];
    pw2 = *(const float4*)&wvb[(I64)(w_k0 + 16) * HDIM + w_c * 4];
    pw3 = *(const float4*)&wvb[(I64)(w_k0 + 24) * HDIM + w_c * 4];

    for (int s = 0; s < 32; ++s) {
      __syncthreads();
      *(float4*)&sA[a_row0][a_kq * 4] = pa0;
      *(float4*)&sA[a_row1][a_kq * 4] = pa1;
      *(float4*)&sA[a_row2][a_kq * 4] = pa2;
      *(float4*)&sA[a_row3][a_kq * 4] = pa3;
      if (t < 128) *(float4*)&sA[a_row4][a_kq * 4] = pa4;
      *(float4*)&sW[w_k0 +  0][w_c * 4] = pw0;
      *(float4*)&sW[w_k0 +  8][w_c * 4] = pw1;
      *(float4*)&sW[w_k0 + 16][w_c * 4] = pw2;
      *(float4*)&sW[w_k0 + 24][w_c * 4] = pw3;
      __syncthreads();
      if (s + 1 < 32) {
        int k0 = (s + 1) * 32;
        pa0 = *(const float4*)&ptb[(I64)a_row0 * DIM + k0 + a_kq * 4];
        pa1 = *(const float4*)&ptb[(I64)a_row1 * DIM + k0 + a_kq * 4];
        pa2 = *(const float4*)&ptb[(I64)a_row2 * DIM + k0 + a_kq * 4];
        pa3 = *(const float4*)&ptb[(I64)a_row3 * DIM + k0 + a_kq * 4];
        if (t < 128) pa4 = *(const float4*)&ptb[(I64)a_row4 * DIM + k0 + a_kq * 4];
        pw0 = *(const float4*)&wvb[(I64)(k0 + w_k0 +  0) * HDIM + w_c * 4];
        pw1 = *(const float4*)&wvb[(I64)(k0 + w_k0 +  8) * HDIM + w_c * 4];
        pw2 = *(const float4*)&wvb[(I64)(k0 + w_k0 + 16) * HDIM + w_c * 4];
        pw3 = *(const float4*)&wvb[(I64)(k0 + w_k0 + 24) * HDIM + w_c * 4];
      }
      #pragma unroll 2
      for (int kk4 = 0; kk4 < 8; ++kk4) {
        float4 af[9];
        #pragma unroll
        for (int i = 0; i < 9; ++i)
          af[i] = *(const float4*)&sA[trow * 9 + i][kk4 * 4];
        float4 w0[4], w1[4];
        #pragma unroll
        for (int m = 0; m < 4; ++m) {
          w0[m] = *(const float4*)&sW[kk4 * 4 + m][tcol * 4];
          w1[m] = *(const float4*)&sW[kk4 * 4 + m][64 + tcol * 4];
        }
        #pragma unroll
        for (int i = 0; i < 9; ++i) {
          #pragma unroll
          for (int m = 0; m < 4; ++m) {
            float a = ((const float*)&af[i])[m];
            acc[i][0] = fmaf(a, w0[m].x, acc[i][0]);
            acc[i][1] = fmaf(a, w0[m].y, acc[i][1]);
            acc[i][2] = fmaf(a, w0[m].z, acc[i][2]);
            acc[i][3] = fmaf(a, w0[m].w, acc[i][3]);
            acc[i][4] = fmaf(a, w1[m].x, acc[i][4]);
            acc[i][5] = fmaf(a, w1[m].y, acc[i][5]);
            acc[i][6] = fmaf(a, w1[m].z, acc[i][6]);
            acc[i][7] = fmaf(a, w1[m].w, acc[i][7]);
          }
        }
      }
    }
    float* hid = ws + WS_HID + ((I64)b * NTOK + n0) * HDIM;
    #pragma unroll
    for (int i = 0; i < 9; ++i) {
      int row = trow * 9 + i;
      float4 va = {acc[i][0], acc[i][1], acc[i][2], acc[i][3]};
      float4 vb = {acc[i][4], acc[i][5], acc[i][6], acc[i][7]};
      *(float4*)&hid[(I64)row * HDIM + col0 + tcol * 4] = va;
      *(float4*)&hid[(I64)row * HDIM + col0 + 64 + tcol * 4] = vb;
    }
  } else if (gid < HIDBLK + QBLK) {
    // ---- q partial GEMV ----
    int g = gid - HIDBLK;
    int b = g >> 5, r = g & 31;
    int qb = r >> 1, ih = r & 1;
    int base = ih * 2048;
    float* qs = smem;
    float (*sp)[64] = (float(*)[64])(smem + 2048);
    const float4* s4 = (const float4*)(qe + (I64)b * QDIM + base);
    *(float4*)&qs[t * 4] = s4[t];
    *(float4*)&qs[(t + 256) * 4] = s4[t + 256];
    __syncthreads();
    int dl = t & 63, ig = t >> 6;
    int d = qb * 64 + dl;
    const float* wq = Wq + d;
    float a0 = 0.f, a1 = 0.f, a2 = 0.f, a3 = 0.f;
    float a4 = 0.f, a5 = 0.f, a6 = 0.f, a7 = 0.f;
    for (int i = ig; i < 2048; i += 32) {
      a0 = fmaf(qs[i],      wq[(I64)(base + i) * HDIM],      a0);
      a1 = fmaf(qs[i + 4],  wq[(I64)(base + i + 4) * HDIM],  a1);
      a2 = fmaf(qs[i + 8],  wq[(I64)(base + i + 8) * HDIM],  a2);
      a3 = fmaf(qs[i + 12], wq[(I64)(base + i + 12) * HDIM], a3);
      a4 = fmaf(qs[i + 16], wq[(I64)(base + i + 16) * HDIM], a4);
      a5 = fmaf(qs[i + 20], wq[(I64)(base + i + 20) * HDIM], a5);
      a6 = fmaf(qs[i + 24], wq[(I64)(base + i + 24) * HDIM], a6);
      a7 = fmaf(qs[i + 28], wq[(I64)(base + i + 28) * HDIM], a7);
    }
    sp[ig][dl] = ((a0 + a1) + (a2 + a3)) + ((a4 + a5) + (a6 + a7));
    __syncthreads();
    if (t < 64) {
      float s2 = (sp[0][t] + sp[1][t]) + (sp[2][t] + sp[3][t]);
      int dd = qb * 64 + t;
      ws[(ih ? WS_Q2 : WS_Q) + (I64)b * HDIM + dd] = s2 + (ih ? 0.f : bq[dd]);
    }
  } else {
    // ---- mask 16x16 block sums ----
    int g = gid - (HIDBLK + QBLK);
    int yband = g % 24;
    int bm = g / 24;
    float (*sm)[96] = (float(*)[96])smem;
    const float4* src = (const float4*)(masks + (I64)bm * (HMASK * WMASK) + (I64)yband * 16 * WMASK);
    #pragma unroll
    for (int j = 0; j < 6; ++j) {
      int f = t + 256 * j;
      float4 v = src[f];
      sm[f / 96][f % 96] = (v.x + v.y) + (v.z + v.w);
    }
    __syncthreads();
    if (t < 24) {
      float tt = 0.f;
      #pragma unroll
      for (int rr = 0; rr < 16; ++rr)
        #pragma unroll
        for (int c = 0; c < 4; ++c) tt += sm[rr][t * 4 + c];
      ws[WS_BS + (I64)bm * GNUM + yband * 24 + t] = tt;
    }
  }
}

// ======================== K2: per-batch small ops (LDS-staged) ========================
#define MGPAD 580
__global__ __launch_bounds__(256) void k_perbatch(
    const float* __restrict__ bs, const float* __restrict__ scores,
    const float* __restrict__ W1, const float* __restrict__ b1,
    float* __restrict__ ws, float* __restrict__ out) {
  int b = blockIdx.x;
  int t = threadIdx.x;
  __shared__ float s_mg[KREG][MGPAD];
  __shared__ float s_sc[NMASK];
  __shared__ float s_msum[NMASK];
  __shared__ int   s_order[NMASK];
  __shared__ float s_sck[KREG];
  __shared__ int   s_valid[KREG];
  __shared__ int   s_midx[KREG];
  __shared__ float s_rowsum[KREG];
  __shared__ float s_pp[GNUM];
  __shared__ float s_geom[KREG][5];
  __shared__ float s_red[64];
  __shared__ int   s_gv;
  __shared__ float s_ppsum;

  {
    int m = t >> 2, q = t & 3;
    const float4* p = (const float4*)(bs + ((I64)b * NMASK + m) * GNUM) + q * 36;
    float s = 0.f;
    #pragma unroll 4
    for (int j = 0; j < 36; ++j) {
      float4 v = p[j];
      s += v.x; s += v.y; s += v.z; s += v.w;
    }
    s += __shfl_xor(s, 1);
    s += __shfl_xor(s, 2);
    if (q == 0) s_msum[m] = s;
  }
  if (t < NMASK) s_sc[t] = scores[b * NMASK + t];
  __syncthreads();
  if (t == 0) {
    int g = 0;
    for (int m = 0; m < NMASK; ++m) g |= (s_msum[m] > 0.f) ? 1 : 0;
    s_gv = g;
  }
  if (t < NMASK) {
    float v = s_sc[t];
    int r = 0;
    for (int j = 0; j < NMASK; ++j) {
      float vj = s_sc[j];
      r += (vj > v) || (vj == v && j < t);
    }
    s_order[r] = t;
  }
  __syncthreads();
  const int gv = s_gv;
  if (t < KREG) {
    int m = s_order[t];
    float sc = s_sc[m];
    int valid = (sc >= 0.5f) ? 1 : 0;
    s_midx[t] = m;
    s_valid[t] = valid;
    float sck = gv ? (valid ? sc : 0.f) : 1.f;
    s_sck[t] = sck;
    ws[WS_SCK + b * KREG + t] = sck;
  }
  __syncthreads();
  {
    int k = t >> 3, sub = t & 7;
    const float inv256 = 1.f / 256.f;
    const float invN = 1.f / 576.f;
    float scale = gv ? (s_valid[k] ? inv256 : 0.f) : 0.f;
    float addv  = gv ? 0.f : invN;
    const float4* src = (const float4*)(bs + ((I64)b * NMASK + s_midx[k]) * GNUM) + sub * 18;
    float* dst = &s_mg[k][sub * 72];
    #pragma unroll 3
    for (int j = 0; j < 18; ++j) {
      float4 v = src[j];
      v.x = v.x * scale + addv;
      v.y = v.y * scale + addv;
      v.z = v.z * scale + addv;
      v.w = v.w * scale + addv;
      *(float4*)(dst + j * 4) = v;
    }
  }
  __syncthreads();
  {
    int k = t >> 3, sub = t & 7;
    float part = 0.f;
    for (int n = sub; n < GNUM; n += 8) part += fmaxf(s_mg[k][n], 0.f);
    part += __shfl_xor(part, 1);
    part += __shfl_xor(part, 2);
    part += __shfl_xor(part, 4);
    if (sub == 0) s_rowsum[k] = part;
  }
  __syncthreads();
  for (int idx = t; idx < KREG * GNUM; idx += 256) {
    int k = idx / GNUM, n = idx - k * GNUM;
    float v = fmaxf(s_mg[k][n], 0.f);
    ws[WS_NMAT + ((I64)b * KREG + k) * GNUM + n] = v / fmaxf(s_rowsum[k], 1e-6f);
  }
  for (int n = t; n < GNUM; n += 256) {
    float raw = 0.f;
    #pragma unroll
    for (int k = 0; k < KREG; ++k) raw = fmaf(s_mg[k][n], s_sck[k], raw);
    s_pp[n] = fmaxf(raw, 0.f);
  }
  __syncthreads();
  if (t < 64) {
    float s = 0.f;
    for (int n = t; n < GNUM; n += 64) s += s_pp[n];
    s_red[t] = s;
  }
  __syncthreads();
  if (t == 0) {
    float s = 0.f;
    for (int i = 0; i < 64; ++i) s += s_red[i];
    s_ppsum = s;
  }
  __syncthreads();
  {
    const float invN = 1.f / 576.f;
    float den = fmaxf(s_ppsum, 1e-6f);
    for (int n = t; n < GNUM; n += 256) {
      float v = gv ? (s_pp[n] / den) : invN;
      ws[WS_PP + b * GNUM + n] = v;
      out[OFF_PP + b * GNUM + n] = v;
    }
  }
  {
    int k = t >> 3, sub = t & 7;
    unsigned colmask = 0u;
    int ymin = GH, ymax = -1, cnt = 0;
    #pragma unroll
    for (int yy = 0; yy < 3; ++yy) {
      int y = sub * 3 + yy;
      unsigned rowm = 0u;
      for (int x = 0; x < GW; ++x)
        if (s_mg[k][y * GW + x] > 0.05f) rowm |= (1u << x);
      if (rowm) { if (y < ymin) ymin = y; if (y > ymax) ymax = y; }
      colmask |= rowm;
      cnt += __popc(rowm);
    }
    #pragma unroll
    for (int off = 1; off < 8; off <<= 1) {
      colmask |= (unsigned)__shfl_xor((int)colmask, off);
      cnt += __shfl_xor(cnt, off);
      int o1 = __shfl_xor(ymin, off); ymin = (o1 < ymin) ? o1 : ymin;
      int o2 = __shfl_xor(ymax, off); ymax = (o2 > ymax) ? o2 : ymax;
    }
    if (sub == 0) {
      float g0, g1, g2, g3, g4;
      if (cnt > 0) {
        int xmin = __ffs(colmask) - 1;
        int xmax = 31 - __clz(colmask);
        g0 = (float)xmin / 23.f;
        g1 = (float)ymin / 23.f;
        g2 = (float)xmax / 23.f;
        g3 = (float)ymax / 23.f;
        g4 = (float)cnt / 576.f;
      } else { g0 = g1 = g2 = g3 = g4 = 0.f; }
      s_geom[k][0] = g0; s_geom[k][1] = g1; s_geom[k][2] = g2;
      s_geom[k][3] = g3; s_geom[k][4] = g4;
    }
  }
  __syncthreads();
  for (int idx = t; idx < KREG * HDIM; idx += 256) {
    int k = idx >> 10, j = idx & 1023;
    float x = 0.f;
    #pragma unroll
    for (int i = 0; i < 5; ++i) x += s_geom[k][i] * W1[i * HDIM + j];
    x += b1[j];
    float sg = 1.f / (1.f + expf(-x));
    ws[WS_H1 + ((I64)b * KREG + k) * HDIM + j] = x * sg;
  }
  if (t == 0) {
    float g = gv ? 1.f : 0.f;
    ws[WS_GV + b] = g;
    out[OFF_GV + b] = g;
  }
}

// ======================== K3: region + colsum + epilogue (merged) ========================
__global__ __launch_bounds__(512) void k_regepi(
    const float* __restrict__ pt, const float* __restrict__ W2,
    const float* __restrict__ b2, const float* __restrict__ te,
    const float* __restrict__ bv, const float* __restrict__ bp,
    const float* __restrict__ Wp, const float* __restrict__ Wo,
    const float* __restrict__ bo,
    float* __restrict__ ws, float* __restrict__ out) {
  int blk = blockIdx.x;
  int t = threadIdx.x;
  if (blk < 512) {
    int b = blk >> 6, kg = (blk >> 3) & 7, dg = blk & 7;
    int dl = t & 127;
    int qh = t >> 7;
    int d = dg * 128 + dl;
    const float* nmb = ws + WS_NMAT + ((I64)b * KREG + kg * 4) * GNUM;
    const float* h1b = ws + WS_H1 + ((I64)b * KREG + kg * 4) * HDIM;
    float accP[4] = {0, 0, 0, 0};
    float accG[4] = {0, 0, 0, 0};
    float accS = 0.f;
    int n0 = qh * 144, n1 = n0 + 144;
    for (int n = n0; n < n1; ++n) {
      float p = pt[((I64)b * NTOK + n) * DIM + d];
      accS += p;
      #pragma unroll
      for (int kk = 0; kk < 4; ++kk)
        accP[kk] = fmaf(nmb[kk * GNUM + n], p, accP[kk]);
    }
    int j0 = qh * 256, j1 = j0 + 256;
    for (int j = j0; j < j1; ++j) {
      float wv = W2[(I64)j * DIM + d];
      #pragma unroll
      for (int kk = 0; kk < 4; ++kk)
        accG[kk] = fmaf(h1b[kk * HDIM + j], wv, accG[kk]);
    }
    __shared__ float cmbP[4][4][128];
    __shared__ float cmbG[4][4][128];
    __shared__ float cmbS[4][128];
    #pragma unroll
    for (int kk = 0; kk < 4; ++kk) {
      cmbP[qh][kk][dl] = accP[kk];
      cmbG[qh][kk][dl] = accG[kk];
    }
    cmbS[qh][dl] = accS;
    __syncthreads();
    if (qh == 0) {
      float bb = b2[d], t0 = te[d];
      #pragma unroll
      for (int kk = 0; kk < 4; ++kk) {
        int k = kg * 4 + kk;
        float P = (cmbP[0][kk][dl] + cmbP[1][kk][dl]) + (cmbP[2][kk][dl] + cmbP[3][kk][dl]);
        float G = (cmbG[0][kk][dl] + cmbG[1][kk][dl]) + (cmbG[2][kk][dl] + cmbG[3][kk][dl]);
        float val = P * ws[WS_SCK + b * KREG + k] + G + bb + t0;
        out[OFF_REG + ((I64)b * KREG + k) * DIM + d] = val;
        out[OFF_VIS + ((I64)b * 161 + k) * DIM + d] = val;
      }
      if (kg == 0)
        ws[WS_CS + (I64)b * DIM + d] =
            (cmbS[0][dl] + cmbS[1][dl]) + (cmbS[2][dl] + cmbS[3][dl]);
    }
  } else {
    int g = (blk - 512) * 32 + (t >> 4);
    int l = t & 15;
    int b = g / NTOK, n = g % NTOK;
    const float* hid = ws + WS_HID + (I64)g * HDIM;
    const float* q1 = ws + WS_Q + (I64)b * HDIM;
    const float* q2 = ws + WS_Q2 + (I64)b * HDIM;
    float ppv = ws[WS_PP + b * GNUM + n];
    float ssum = 0.f;
    #pragma unroll 4
    for (int j = 0; j < 16; ++j) {
      int c = l * 64 + j * 4;
      float4 h4 = *(const float4*)&hid[c];
      float4 b4 = *(const float4*)&bv[c];
      float4 p4 = *(const float4*)&bp[c];
      float4 w4 = *(const float4*)&Wp[c];
      float4 o4 = *(const float4*)&Wo[c];
      float4 qa = *(const float4*)&q1[c];
      float4 qb = *(const float4*)&q2[c];
      ssum = fmaf(o4.x, tanhf(h4.x + b4.x + p4.x + qa.x + qb.x + ppv * w4.x), ssum);
      ssum = fmaf(o4.y, tanhf(h4.y + b4.y + p4.y + qa.y + qb.y + ppv * w4.y), ssum);
      ssum = fmaf(o4.z, tanhf(h4.z + b4.z + p4.z + qa.z + qb.z + ppv * w4.z), ssum);
      ssum = fmaf(o4.w, tanhf(h4.w + b4.w + p4.w + qa.w + qb.w + ppv * w4.w), ssum);
    }
    ssum += __shfl_xor(ssum, 1);
    ssum += __shfl_xor(ssum, 2);
    ssum += __shfl_xor(ssum, 4);
    ssum += __shfl_xor(ssum, 8);
    if (l == 0) ws[WS_RS + g] = ssum + bo[0];
  }
}

// ======================== K4: softmax + stable top-k ========================
__global__ __launch_bounds__(576) void k_soft2(float* __restrict__ ws, float* __restrict__ out) {
  int b = blockIdx.x, t = threadIdx.x;
  __shared__ float s_rs[NTOK];
  __shared__ float s_w[9];
  __shared__ float s_max, s_sum;
  s_rs[t] = ws[WS_RS + b * NTOK + t];
  __syncthreads();
  float v = s_rs[t];
  int r = 0;
  for (int j = 0; j < NTOK; ++j) {
    float vj = s_rs[j];
    r += (vj > v) || (vj == v && j < t);
  }
  float m = v;
  for (int off = 1; off < 64; off <<= 1) m = fmaxf(m, __shfl_xor(m, off));
  if ((t & 63) == 0) s_w[t >> 6] = m;
  __syncthreads();
  if (t == 0) {
    float mm = s_w[0];
    for (int i = 1; i < 9; ++i) mm = fmaxf(mm, s_w[i]);
    s_max = mm;
  }
  __syncthreads();
  float e = expf(v - s_max);
  float s = e;
  for (int off = 1; off < 64; off <<= 1) s += __shfl_xor(s, off);
  if ((t & 63) == 0) s_w[t >> 6] = s;
  __syncthreads();
  if (t == 0) {
    float ss = 0.f;
    for (int i = 0; i < 9; ++i) ss += s_w[i];
    s_sum = ss;
  }
  __syncthreads();
  out[OFF_RW + b * NTOK + t] = e / s_sum;
  if (r < CCTX) out[OFF_SEL + b * CCTX + r] = (float)t;
}

// ======================== K5: context gather + background (parallel bg) ========================
__global__ __launch_bounds__(256) void k_post(const float* __restrict__ pt, const float* __restrict__ te,
                                              const float* __restrict__ ws, const float* __restrict__ outr,
                                              float* __restrict__ out) {
  int rr = blockIdx.x, b = blockIdx.y;
  if (rr < CCTX) {
    int d = threadIdx.x * 4;
    int idx = (int)outr[OFF_SEL + b * CCTX + rr];
    float4 v = *(const float4*)&pt[((I64)b * NTOK + idx) * DIM + d];
    float4 e = *(const float4*)&te[DIM + d];
    v.x += e.x; v.y += e.y; v.z += e.z; v.w += e.w;
    *(float4*)&out[OFF_CTX + ((I64)b * CCTX + rr) * DIM + d] = v;
    *(float4*)&out[OFF_VIS + ((I64)b * 161 + KREG + rr) * DIM + d] = v;
  } else {
    int dl = threadIdx.x & 63;
    int rg = threadIdx.x >> 6;
    __shared__ float4 cmb[4][64];
    #pragma unroll
    for (int dd = 0; dd < 4; ++dd) {
      int d = (dd * 64 + dl) * 4;
      float4 s = {0.f, 0.f, 0.f, 0.f};
      for (int r = rg * 32; r < rg * 32 + 32; ++r) {
        int idx = (int)outr[OFF_SEL + b * CCTX + r];
        float4 v = *(const float4*)&pt[((I64)b * NTOK + idx) * DIM + d];
        s.x += v.x; s.y += v.y; s.z += v.z; s.w += v.w;
      }
      cmb[rg][dl] = s;
      __syncthreads();
      if (rg == 0) {
        float4 s0 = cmb[0][dl], s1 = cmb[1][dl], s2 = cmb[2][dl], s3 = cmb[3][dl];
        float4 cs = *(const float4*)&ws[WS_CS + (I64)b * DIM + d];
        const float rinv = 1.f / 448.f;
        float4 e = *(const float4*)&te[2 * DIM + d];
        float4 o;
        o.x = (cs.x - ((s0.x + s1.x) + (s2.x + s3.x))) * rinv + e.x;
        o.y = (cs.y - ((s0.y + s1.y) + (s2.y + s3.y))) * rinv + e.y;
        o.z = (cs.z - ((s0.z + s1.z) + (s2.z + s3.z))) * rinv + e.z;
        o.w = (cs.w - ((s0.w + s1.w) + (s2.w + s3.w))) * rinv + e.w;
        *(float4*)&out[OFF_BG + (I64)b * DIM + d] = o;
        *(float4*)&out[OFF_VIS + ((I64)b * 161 + 160) * DIM + d] = o;
      }
      __syncthreads();
    }
  }
}

// ======================== launcher ========================
extern "C" void kernel_launch(void* const* d_in, const int* in_sizes, int n_in,
                              void* d_out, int out_size, void* d_ws, size_t ws_size,
                              hipStream_t stream) {
  (void)in_sizes; (void)n_in; (void)out_size; (void)ws_size;
  const float* pt     = (const float*)d_in[0];
  const float* masks  = (const float*)d_in[1];
  const float* scores = (const float*)d_in[2];
  const float* qe     = (const float*)d_in[3];
  const float* W1     = (const float*)d_in[4];
  const float* b1     = (const float*)d_in[5];
  const float* W2     = (const float*)d_in[6];
  const float* b2     = (const float*)d_in[7];
  const float* Wv     = (const float*)d_in[8];
  const float* bv     = (const float*)d_in[9];
  const float* Wp     = (const float*)d_in[10];
  const float* bp     = (const float*)d_in[11];
  const float* Wq     = (const float*)d_in[12];
  const float* bq     = (const float*)d_in[13];
  const float* Wo     = (const float*)d_in[14];
  const float* bo     = (const float*)d_in[15];
  const float* te     = (const float*)d_in[16];
  float* out = (float*)d_out;
  float* ws  = (float*)d_ws;

  k_mega<<<dim3(MEGA_GRID), dim3(256), 0, stream>>>(masks, qe, Wq, bq, pt, Wv, ws);
  k_perbatch<<<dim3(NB), dim3(256), 0, stream>>>(ws + WS_BS, scores, W1, b1, ws, out);
  k_regepi<<<dim3(512 + 144), dim3(512), 0, stream>>>(pt, W2, b2, te, bv, bp, Wp, Wo, bo, ws, out);
  k_soft2<<<dim3(NB), dim3(576), 0, stream>>>(ws, out);
  k_post<<<dim3(CCTX + 1, NB), dim3(256), 0, stream>>>(pt, te, ws, out, out);
}